// Round 1
// baseline (3149.754 us; speedup 1.0000x reference)
//
#include <hip/hip_runtime.h>

// SentenceEncodingRNN2: 2-layer BiLSTM (T=256,B=128,D=300,H=256) + attention pooling.
// Round 10: pipelined lstm_rec. The block's 8 batches split into sub-groups A (kc<4)
//   and B (kc>=4); per step: compute A -> spin-stage B(t-1) (latency covered by A's
//   compute) -> barrier -> compute B -> spin-stage A(t) (covered by B) -> barrier.
//   Ring store->load visibility latency (~2.5us/step exposed before) now overlaps
//   FMA work. Single LDS h buffer (phases barrier-separated). blockIdx remapped to
//   (s,d,g) so the 8 s-slices sharing (d,g) sit on one XCD (ring traffic XCD-local).
//   R9 counters: lstm_rec 272us/dispatch x8 = 74% of total; VALU 50%, HBM 6.6%,
//   latency-bound on h broadcast. proj_gemm2 / attn_gemm / attn_final unchanged.

#define T_ 256
#define B_ 128
#define D_ 300
#define H_ 256
#define G4H 1024   // 4*H
#define H2 512     // 2*H
#define TC 64      // time-chunk length
#define LDK 40     // LDS k-stride in bf16 elements (80 B rows: 16B-aligned frags)

typedef __attribute__((ext_vector_type(8))) short bf16x8;
typedef __attribute__((ext_vector_type(4))) short short4v;
typedef __attribute__((ext_vector_type(4))) float f32x4;

// ---------------- helpers ----------------
__device__ __forceinline__ float sigf(float x) { return 1.f / (1.f + __expf(-x)); }
__device__ __forceinline__ float tanhfast(float x) { return 2.f / (1.f + __expf(-2.f * x)) - 1.f; }

// hi/lo bf16 split of fp32 (truncation; lo captures the residual)
__device__ __forceinline__ short hi_bf16(float x) {
  return (short)(__float_as_uint(x) >> 16);
}
__device__ __forceinline__ short lo_bf16(float x) {
  float lo = x - __uint_as_float(__float_as_uint(x) & 0xFFFF0000u);
  return (short)(__float_as_uint(lo) >> 16);
}

__device__ __forceinline__ void split_f4(const float4 v, short* hp, short* lp) {
  short4v h, l;
  h.x = hi_bf16(v.x); l.x = lo_bf16(v.x);
  h.y = hi_bf16(v.y); l.y = lo_bf16(v.y);
  h.z = hi_bf16(v.z); l.z = lo_bf16(v.z);
  h.w = hi_bf16(v.w); l.w = lo_bf16(v.w);
  *(short4v*)hp = h;
  *(short4v*)lp = l;
}

// ---------------- dual-direction projection GEMM, split-bf16 MFMA ----------------
// C[lm][n] = sum_k X[srow(lm)][k]*W[n][k] + b1[n]+b2[n]; lm = chunk-local scan index.
// grid: (N/128, TC, 2 dirs); block 256 = 4 waves in 2x2 (64x64 each).
__global__ __launch_bounds__(256, 2) void proj_gemm2(
    const float* __restrict__ X,
    const float* __restrict__ W0, const float* __restrict__ W1,
    const float* __restrict__ b1f, const float* __restrict__ b2f,
    const float* __restrict__ b1r, const float* __restrict__ b2r,
    float* __restrict__ C0, float* __restrict__ C1,
    int N, int K, const int* __restrict__ lengths, int t0)
{
  __shared__ short Xh[128 * LDK], Xl[128 * LDK];
  __shared__ short Wh[128 * LDK], Wl[128 * LDK];
  const int rev = blockIdx.z;
  const float* __restrict__ W = rev ? W1 : W0;
  const float* __restrict__ bias1 = rev ? b1r : b1f;
  const float* __restrict__ bias2 = rev ? b2r : b2f;
  float* __restrict__ C = rev ? C1 : C0;

  const int tid = threadIdx.x;
  const int m0 = blockIdx.y * 128, n0 = blockIdx.x * 128;
  const int s_step = t0 + blockIdx.y;

  // staging: thread covers rows sr+32p, cols sc..sc+3 of the 128x32 k-tile
  const int sr = tid >> 3;
  const int sc = (tid & 7) * 4;
  const float* px[4];
  const float* pw[4];
#pragma unroll
  for (int p = 0; p < 4; p++) {
    const int r = sr + p * 32;          // r == batch index within tile
    int ss = s_step;
    if (rev) {
      int lb = lengths[r]; if (lb < 1) lb = 1;
      ss = (s_step < lb) ? (lb - 1 - s_step) : s_step;
    }
    px[p] = X + (size_t)(ss * 128 + r) * K;
    pw[p] = W + (size_t)(n0 + r) * K;
  }

  const int lane = tid & 63, w = tid >> 6;
  const int mb = (w & 1) * 64, nb = (w >> 1) * 64;
  const int r16 = lane & 15, quad = lane >> 4;

  f32x4 acc[4][4];
#pragma unroll
  for (int i = 0; i < 4; i++)
#pragma unroll
    for (int j = 0; j < 4; j++) acc[i][j] = (f32x4){0.f, 0.f, 0.f, 0.f};

  for (int k0 = 0; k0 < K; k0 += 32) {
    const int gk = k0 + sc;
    const bool kin = (gk < K);          // K % 4 == 0 -> whole float4 in/out
#pragma unroll
    for (int p = 0; p < 4; p++) {
      float4 xv = {0.f, 0.f, 0.f, 0.f}, wv = {0.f, 0.f, 0.f, 0.f};
      if (kin) { xv = *(const float4*)(px[p] + gk); wv = *(const float4*)(pw[p] + gk); }
      const int ro = (sr + p * 32) * LDK + sc;
      split_f4(xv, &Xh[ro], &Xl[ro]);
      split_f4(wv, &Wh[ro], &Wl[ro]);
    }
    __syncthreads();

    bf16x8 ah[4], al[4], bh[4], bl[4];
#pragma unroll
    for (int mt = 0; mt < 4; mt++) {
      const int ro = (mb + mt * 16 + r16) * LDK + quad * 8;
      ah[mt] = *(const bf16x8*)&Xh[ro];
      al[mt] = *(const bf16x8*)&Xl[ro];
    }
#pragma unroll
    for (int nt = 0; nt < 4; nt++) {
      const int ro = (nb + nt * 16 + r16) * LDK + quad * 8;
      bh[nt] = *(const bf16x8*)&Wh[ro];
      bl[nt] = *(const bf16x8*)&Wl[ro];
    }
#pragma unroll
    for (int mt = 0; mt < 4; mt++)
#pragma unroll
      for (int nt = 0; nt < 4; nt++) {
        acc[mt][nt] = __builtin_amdgcn_mfma_f32_16x16x32_bf16(ah[mt], bh[nt], acc[mt][nt], 0, 0, 0);
        acc[mt][nt] = __builtin_amdgcn_mfma_f32_16x16x32_bf16(ah[mt], bl[nt], acc[mt][nt], 0, 0, 0);
        acc[mt][nt] = __builtin_amdgcn_mfma_f32_16x16x32_bf16(al[mt], bh[nt], acc[mt][nt], 0, 0, 0);
      }
    __syncthreads();
  }

  // epilogue: C/D layout row = quad*4+reg (m), col = lane&15 (n)  [m89-verified]
  float bsum[4];
#pragma unroll
  for (int nt = 0; nt < 4; nt++) {
    const int col = n0 + nb + nt * 16 + r16;
    bsum[nt] = bias1[col] + bias2[col];
  }
#pragma unroll
  for (int mt = 0; mt < 4; mt++) {
    const int row = m0 + mb + mt * 16 + quad * 4;
#pragma unroll
    for (int nt = 0; nt < 4; nt++) {
      const int col = n0 + nb + nt * 16 + r16;
      float* Cp = C + (size_t)row * N + col;
#pragma unroll
      for (int reg = 0; reg < 4; reg++)
        Cp[(size_t)reg * N] = acc[mt][nt][reg] + bsum[nt];
    }
  }
}

// ---------------- attention score GEMM, split-bf16 MFMA, fused tanh*ctx ----------
// scores[m] += sum_n tanh(h2[m]@mlp_w^T + b)[n] * ctx[n]
__global__ __launch_bounds__(256, 2) void attn_gemm(
    const float* __restrict__ X, const float* __restrict__ W,
    const float* __restrict__ mlp_b, const float* __restrict__ ctx,
    float* __restrict__ scores, int M, int N, int K)
{
  __shared__ short Xh[128 * LDK], Xl[128 * LDK];
  __shared__ short Wh[128 * LDK], Wl[128 * LDK];
  const int tid = threadIdx.x;
  const int m0 = blockIdx.y * 128, n0 = blockIdx.x * 128;

  const int sr = tid >> 3;
  const int sc = (tid & 7) * 4;
  const float* px[4];
  const float* pw[4];
#pragma unroll
  for (int p = 0; p < 4; p++) {
    px[p] = X + (size_t)(m0 + sr + p * 32) * K;
    pw[p] = W + (size_t)(n0 + sr + p * 32) * K;
  }

  const int lane = tid & 63, w = tid >> 6;
  const int mb = (w & 1) * 64, nb = (w >> 1) * 64;
  const int r16 = lane & 15, quad = lane >> 4;

  f32x4 acc[4][4];
#pragma unroll
  for (int i = 0; i < 4; i++)
#pragma unroll
    for (int j = 0; j < 4; j++) acc[i][j] = (f32x4){0.f, 0.f, 0.f, 0.f};

  for (int k0 = 0; k0 < K; k0 += 32) {
    const int gk = k0 + sc;
#pragma unroll
    for (int p = 0; p < 4; p++) {
      float4 xv = *(const float4*)(px[p] + gk);
      float4 wv = *(const float4*)(pw[p] + gk);
      const int ro = (sr + p * 32) * LDK + sc;
      split_f4(xv, &Xh[ro], &Xl[ro]);
      split_f4(wv, &Wh[ro], &Wl[ro]);
    }
    __syncthreads();

    bf16x8 ah[4], al[4], bh[4], bl[4];
#pragma unroll
    for (int mt = 0; mt < 4; mt++) {
      const int ro = (mb + mt * 16 + r16) * LDK + quad * 8;
      ah[mt] = *(const bf16x8*)&Xh[ro];
      al[mt] = *(const bf16x8*)&Xl[ro];
    }
#pragma unroll
    for (int nt = 0; nt < 4; nt++) {
      const int ro = (nb + nt * 16 + r16) * LDK + quad * 8;
      bh[nt] = *(const bf16x8*)&Wh[ro];
      bl[nt] = *(const bf16x8*)&Wl[ro];
    }
#pragma unroll
    for (int mt = 0; mt < 4; mt++)
#pragma unroll
      for (int nt = 0; nt < 4; nt++) {
        acc[mt][nt] = __builtin_amdgcn_mfma_f32_16x16x32_bf16(ah[mt], bh[nt], acc[mt][nt], 0, 0, 0);
        acc[mt][nt] = __builtin_amdgcn_mfma_f32_16x16x32_bf16(ah[mt], bl[nt], acc[mt][nt], 0, 0, 0);
        acc[mt][nt] = __builtin_amdgcn_mfma_f32_16x16x32_bf16(al[mt], bh[nt], acc[mt][nt], 0, 0, 0);
      }
    __syncthreads();
  }

  // epilogue: tanh(acc + b)*ctx, reduce over n (4 nt in-thread, then 16 lanes)
  float bb4[4], cc4[4];
#pragma unroll
  for (int nt = 0; nt < 4; nt++) {
    const int col = n0 + nb + nt * 16 + r16;
    bb4[nt] = mlp_b[col];
    cc4[nt] = ctx[col];
  }
#pragma unroll
  for (int mt = 0; mt < 4; mt++) {
#pragma unroll
    for (int reg = 0; reg < 4; reg++) {
      float ssum = 0.f;
#pragma unroll
      for (int nt = 0; nt < 4; nt++)
        ssum += tanhfast(acc[mt][nt][reg] + bb4[nt]) * cc4[nt];
      ssum += __shfl_xor(ssum, 1);
      ssum += __shfl_xor(ssum, 2);
      ssum += __shfl_xor(ssum, 4);
      ssum += __shfl_xor(ssum, 8);
      if (r16 == 0)
        atomicAdd(&scores[m0 + mb + mt * 16 + quad * 4 + reg], ssum);
    }
  }
}

// ---------------- LSTM recurrence chunk (both directions) -- R10 pipelined -------
// blocks: 256 remapped as blk = s*32 + d*16 + g so the 8 s-slices sharing (d,g)
//   (the h-exchange partners) land on the same XCD (blk % 8 identical).
// thread: tid = hh*8 + kc; owns cell (b = g*8+kc, hdim = s*32+hh).
// Sub-group A = batches kc<4, B = kc>=4. Per step:
//   P1 compute A(t), store h_A -> ring
//   P2 spin-stage B(t-1) (covered by P1's compute) + prefetch x(t+1); barrier
//   P3 compute B(t), store h_B -> ring
//   P4 spin-stage A(t) (covered by P3's compute); commit x; barrier
__global__ __launch_bounds__(256, 1) void lstm_rec(
    const float* __restrict__ xgF, const float* __restrict__ xgR,
    const float* __restrict__ whF, const float* __restrict__ whR,
    const int* __restrict__ lengths, float* __restrict__ hout,
    float* __restrict__ ring, float* __restrict__ bbuf, float* __restrict__ cbuf,
    int t0)
{
  __shared__ float ht[2304];          // 8 batches x 288 (8 chunks of 32+4 pad)
  const int tid = threadIdx.x;
  const int blk = blockIdx.x;
  const int s = blk >> 5;             // h-slice: XCD-local remap (partners differ only in s)
  const int d = (blk >> 4) & 1;
  const int g = blk & 15;
  const int hh = tid >> 3;
  const int kc = tid & 7;
  const int b = g * 8 + kc;
  const int hdim = s * 32 + hh;
  const int u_own = kc >> 2;          // which sub-group this thread's cell belongs to
  const float* __restrict__ xg = d ? xgR : xgF;
  const float* __restrict__ wh = d ? whR : whF;

  float wreg[4][32];
#pragma unroll
  for (int gate = 0; gate < 4; gate++) {
    const float* wrow = wh + ((size_t)(gate * 256 + hdim)) * 256 + kc * 32;
#pragma unroll
    for (int j = 0; j < 32; j += 4) {
      float4 v = *(const float4*)(wrow + j);
      wreg[gate][j] = v.x; wreg[gate][j + 1] = v.y;
      wreg[gate][j + 2] = v.z; wreg[gate][j + 3] = v.w;
    }
  }

  float c;
  if (t0 == 0) {
    for (int i = tid; i < 2304; i += 256) ht[i] = 0.f;
    c = 0.f;
  } else {
    const int fi = tid * 8;
    const int b2 = fi >> 8, k2 = fi & 255;
    const float* src = bbuf + ((size_t)d * 128 + g * 8 + b2) * 256 + k2;
    float4 v0 = *(const float4*)(src);
    float4 v1 = *(const float4*)(src + 4);
    float* dst = ht + b2 * 288 + ((k2 >> 5) * 36) + (k2 & 31);
    *(float4*)dst = v0;
    *(float4*)(dst + 4) = v1;
    c = cbuf[((size_t)d * 128 + b) * 256 + hdim];
  }
  int lb = lengths[b]; if (lb < 1) lb = 1;
  __syncthreads();

  const float* xr0 = xg + ((size_t)b) * 1024 + hdim;
  float x0 = xr0[0], x1 = xr0[256], x2 = xr0[512], x3 = xr0[768];

  // staging roles: per sub-group stage = 4 batches x 256 dwords = 4 dwords/thread
  const int sb = (tid >> 5) & 3;      // batch within sub-group
  const int hf = tid >> 7;            // 128-dword half of the h row
  const int kbase = tid & 31;

  const int tend = t0 + TC;
  for (int t = t0; t < tend; t++) {
    const int slot = t - t0;
    const bool last = (t == tend - 1);

    // compute one sub-group: gate matvec from LDS rows [u*4 .. u*4+3]
    auto compute_sub = [&](int u) {
      float part[4][4];
#pragma unroll
      for (int gate = 0; gate < 4; gate++)
#pragma unroll
        for (int q = 0; q < 4; q++) part[gate][q] = 0.f;

#pragma unroll
      for (int q = 0; q < 4; q++) {
        const float* hrow = ht + (u * 4 + q) * 288 + kc * 36;
#pragma unroll
        for (int j = 0; j < 32; j += 4) {
          float4 h4 = *(const float4*)(hrow + j);
#pragma unroll
          for (int gate = 0; gate < 4; gate++) {
            float p = part[gate][q];
            p = fmaf(h4.x, wreg[gate][j],     p);
            p = fmaf(h4.y, wreg[gate][j + 1], p);
            p = fmaf(h4.z, wreg[gate][j + 2], p);
            p = fmaf(h4.w, wreg[gate][j + 3], p);
            part[gate][q] = p;
          }
        }
      }

      // redistributing butterfly over kc bits 1,0 (fold q), then plain fold bit 2
      float m2[4][2];
#pragma unroll
      for (int gate = 0; gate < 4; gate++)
#pragma unroll
        for (int q = 0; q < 2; q++) {
          const float keep = (kc & 2) ? part[gate][q + 2] : part[gate][q];
          const float send = (kc & 2) ? part[gate][q]     : part[gate][q + 2];
          m2[gate][q] = keep + __shfl_xor(send, 2, 8);
        }
      float gs[4];
#pragma unroll
      for (int gate = 0; gate < 4; gate++) {
        const float keep = (kc & 1) ? m2[gate][1] : m2[gate][0];
        const float send = (kc & 1) ? m2[gate][0] : m2[gate][1];
        const float m1 = keep + __shfl_xor(send, 1, 8);
        gs[gate] = m1 + __shfl_xor(m1, 4, 8);
      }

      if (u_own == u) {
        const float si = sigf(gs[0] + x0);
        const float sf = sigf(gs[1] + x1);
        const float tg = tanhfast(gs[2] + x2);
        const float so = sigf(gs[3] + x3);
        c = sf * c + si * tg;
        const float h = so * tanhfast(c);
        if (!last) {
          __hip_atomic_store(&ring[(((size_t)slot * 2 + d) * 128 + b) * 256 + hdim], h,
                             __ATOMIC_RELAXED, __HIP_MEMORY_SCOPE_AGENT);
        } else {
          bbuf[((size_t)d * 128 + b) * 256 + hdim] = h;
        }
        const int tin = d ? ((t < lb) ? (lb - 1 - t) : t) : t;
        hout[((size_t)tin * 128 + b) * 512 + d * 256 + hdim] = h;
      }
    };

    // spin-stage sub-group u's h from ring slot ss into LDS rows [u*4 .. u*4+3]
    auto spin_stage = [&](int u, int ss) {
      const unsigned* srcu = (const unsigned*)(ring +
          (((size_t)ss * 2 + d) * 128 + g * 8 + u * 4 + sb) * 256 + hf * 128 + kbase);
      unsigned uv[4];
      int it = 0;
      for (;;) {
        bool ok = true;
#pragma unroll
        for (int jj = 0; jj < 4; jj++) {
          uv[jj] = __hip_atomic_load(&srcu[32 * jj],
                                     __ATOMIC_RELAXED, __HIP_MEMORY_SCOPE_AGENT);
          ok &= (uv[jj] != 0xFFFFFFFFu);
        }
        if (ok || ++it >= 20000) break;
      }
      float* htw = ht + (u * 4 + sb) * 288 + (hf * 4) * 36 + kbase;
#pragma unroll
      for (int jj = 0; jj < 4; jj++)
        htw[jj * 36] = __uint_as_float(uv[jj]);
    };

    // ---- P1: sub-group A step t ----
    compute_sub(0);

    // ---- P2: prefetch x(t+1); stage B(t-1) (stored during prev iter's P3) ----
    float nx0 = 0.f, nx1 = 0.f, nx2 = 0.f, nx3 = 0.f;
    if (!last) {
      const float* xn = xg + ((size_t)(t + 1 - t0) * 128 + b) * 1024 + hdim;
      nx0 = xn[0]; nx1 = xn[256]; nx2 = xn[512]; nx3 = xn[768];
    }
    if (t > t0) spin_stage(1, slot - 1);
    __syncthreads();

    // ---- P3: sub-group B step t ----
    compute_sub(1);

    // ---- P4: stage A(t) (stored during this iter's P1); commit x ----
    if (!last) {
      spin_stage(0, slot);
      x0 = nx0; x1 = nx1; x2 = nx2; x3 = nx3;
      __syncthreads();
    }
  }
  cbuf[((size_t)d * 128 + b) * 256 + hdim] = c;
}

// ---------------- masked softmax over t + weighted sum ----------------
__global__ __launch_bounds__(256) void attn_final(
    const float* __restrict__ h2, const float* __restrict__ scores,
    const int* __restrict__ lengths, float* __restrict__ out)
{
  __shared__ float sl[256];
  __shared__ float red[256];
  const int b = blockIdx.x, tid = threadIdx.x;
  int lb = lengths[b]; if (lb < 1) lb = 1;
  const float sc = scores[(size_t)tid * 128 + b];
  const bool valid = (tid < lb);
  red[tid] = valid ? sc : -1e30f;
  __syncthreads();
  for (int off = 128; off > 0; off >>= 1) {
    if (tid < off) red[tid] = fmaxf(red[tid], red[tid + off]);
    __syncthreads();
  }
  const float mx = red[0];
  __syncthreads();
  const float p = valid ? __expf(sc - mx) : 0.f;
  red[tid] = p;
  __syncthreads();
  for (int off = 128; off > 0; off >>= 1) {
    if (tid < off) red[tid] += red[tid + off];
    __syncthreads();
  }
  const float inv = 1.f / red[0];
  __syncthreads();
  sl[tid] = p * inv;
  __syncthreads();

  float ax = 0.f, ay = 0.f;
  const int dd = tid * 2;
  for (int t = 0; t < 256; t++) {
    const float w = sl[t];
    if (w != 0.f) {
      const float* row = h2 + ((size_t)t * 128 + b) * 512 + dd;
      ax += w * row[0];
      ay += w * row[1];
    }
  }
  float2 r; r.x = ax; r.y = ay;
  *(float2*)(out + (size_t)b * 512 + dd) = r;
}

// ---------------- launch ----------------
extern "C" void kernel_launch(void* const* d_in, const int* in_sizes, int n_in,
                              void* d_out, int out_size, void* d_ws, size_t ws_size,
                              hipStream_t stream) {
  (void)in_sizes; (void)n_in; (void)out_size; (void)ws_size;
  const float* x        = (const float*)d_in[0];
  const int*   lengths  = (const int*)d_in[1];
  const float* w_ih_l0  = (const float*)d_in[2];
  const float* w_hh_l0  = (const float*)d_in[3];
  const float* b_ih_l0  = (const float*)d_in[4];
  const float* b_hh_l0  = (const float*)d_in[5];
  const float* w_ih_l0r = (const float*)d_in[6];
  const float* w_hh_l0r = (const float*)d_in[7];
  const float* b_ih_l0r = (const float*)d_in[8];
  const float* b_hh_l0r = (const float*)d_in[9];
  const float* w_ih_l1  = (const float*)d_in[10];
  const float* w_hh_l1  = (const float*)d_in[11];
  const float* b_ih_l1  = (const float*)d_in[12];
  const float* b_hh_l1  = (const float*)d_in[13];
  const float* w_ih_l1r = (const float*)d_in[14];
  const float* w_hh_l1r = (const float*)d_in[15];
  const float* b_ih_l1r = (const float*)d_in[16];
  const float* b_hh_l1r = (const float*)d_in[17];
  const float* mlp_w    = (const float*)d_in[18];
  const float* mlp_b    = (const float*)d_in[19];
  const float* ctx      = (const float*)d_in[20];
  float* out = (float*)d_out;

  // workspace layout (floats): ~219 MB
  float* ws = (float*)d_ws;
  const size_t XGC    = (size_t)TC * B_ * G4H;        // 8,388,608
  const size_t H_SZ   = (size_t)T_ * B_ * H2;         // 16,777,216
  const size_t RINGSZ = (size_t)TC * 2 * B_ * H_;     // 4,194,304 floats = 16 MB
  float* xgA    = ws;
  float* xgB    = xgA + XGC;
  float* h1     = xgB + XGC;
  float* h2     = h1 + H_SZ;
  float* ring   = h2 + H_SZ;
  float* bbuf   = ring + RINGSZ;                      // 65,536
  float* cbuf   = bbuf + 65536;                       // 65,536
  float* scores = cbuf + 65536;                       // 32,768

  (void)hipMemsetAsync(scores, 0, 32768 * 4, stream);

  dim3 blk(256);
  const dim3 pgrid(G4H / 128, TC, 2);   // (8, 64, 2 directions)

  // layer 0 (K=300), chunked over time
  for (int c = 0; c < T_ / TC; c++) {
    const int t0 = c * TC;
    proj_gemm2<<<pgrid, blk, 0, stream>>>(x, w_ih_l0, w_ih_l0r,
                                          b_ih_l0, b_hh_l0, b_ih_l0r, b_hh_l0r,
                                          xgA, xgB, G4H, D_, lengths, t0);
    (void)hipMemsetAsync(ring, 0xFF, RINGSZ * 4, stream);   // sentinel = 0xFFFFFFFF
    lstm_rec<<<256, blk, 0, stream>>>(xgA, xgB, w_hh_l0, w_hh_l0r, lengths, h1,
                                      ring, bbuf, cbuf, t0);
  }
  // layer 1 (K=512)
  for (int c = 0; c < T_ / TC; c++) {
    const int t0 = c * TC;
    proj_gemm2<<<pgrid, blk, 0, stream>>>(h1, w_ih_l1, w_ih_l1r,
                                          b_ih_l1, b_hh_l1, b_ih_l1r, b_hh_l1r,
                                          xgA, xgB, G4H, H2, lengths, t0);
    (void)hipMemsetAsync(ring, 0xFF, RINGSZ * 4, stream);
    lstm_rec<<<256, blk, 0, stream>>>(xgA, xgB, w_hh_l1, w_hh_l1r, lengths, h2,
                                      ring, bbuf, cbuf, t0);
  }
  // attention (M=32768, N=512, K=512)
  attn_gemm<<<dim3(H2 / 128, (T_ * B_) / 128), blk, 0, stream>>>(h2, mlp_w, mlp_b, ctx, scores, T_ * B_, H2, H2);
  attn_final<<<B_, blk, 0, stream>>>(h2, scores, lengths, out);
}

// Round 2
// 2385.370 us; speedup vs baseline: 1.3204x; 1.3204x over previous
//
#include <hip/hip_runtime.h>

// SentenceEncodingRNN2: 2-layer BiLSTM (T=256,B=128,D=300,H=256) + attention pooling.
// Round 11: MFMA lstm_rec. R9/R10 post-mortem: VGPR_Count=100 < the 128 VGPRs
//   wreg needs -> scalar-path weights were NOT register-resident; compiler re-loaded
//   them from L1/L2 every step (the unexplained ~3000 VALU cyc/step, VALUBusy 50%).
//   Fix: recurrence matvec as split-bf16 MFMA ([16x256]@[256x128] per block/step,
//   48 MFMAs/wave in 6 indep chains); weights as bf16 hi/lo fragments = 128 VGPR,
//   statically indexed -> resident. Gate layout: wave w == gate w; epilogue via
//   4KB LDS gbuf; cell update per thread. Ring protocol + XCD-local block remap
//   kept; R10's half-step pipeline reverted (it hurt: 272->299us).
//   proj_gemm2 / attn_gemm / attn_final unchanged.

#define T_ 256
#define B_ 128
#define D_ 300
#define H_ 256
#define G4H 1024   // 4*H
#define H2 512     // 2*H
#define TC 64      // time-chunk length
#define LDK 40     // proj/attn LDS k-stride in bf16 (80 B rows)
#define LDA 264    // lstm A-tile LDS k-stride in bf16 (256+8: 2-way max aliasing)

typedef __attribute__((ext_vector_type(8))) short bf16x8;
typedef __attribute__((ext_vector_type(4))) short short4v;
typedef __attribute__((ext_vector_type(4))) float f32x4;

#define MFMA16(a, b, c) __builtin_amdgcn_mfma_f32_16x16x32_bf16(a, b, c, 0, 0, 0)

// ---------------- helpers ----------------
__device__ __forceinline__ float sigf(float x) { return 1.f / (1.f + __expf(-x)); }
__device__ __forceinline__ float tanhfast(float x) { return 2.f / (1.f + __expf(-2.f * x)) - 1.f; }

// hi/lo bf16 split of fp32 (truncation; lo captures the residual)
__device__ __forceinline__ short hi_bf16(float x) {
  return (short)(__float_as_uint(x) >> 16);
}
__device__ __forceinline__ short lo_bf16(float x) {
  float lo = x - __uint_as_float(__float_as_uint(x) & 0xFFFF0000u);
  return (short)(__float_as_uint(lo) >> 16);
}

__device__ __forceinline__ void split_f4(const float4 v, short* hp, short* lp) {
  short4v h, l;
  h.x = hi_bf16(v.x); l.x = lo_bf16(v.x);
  h.y = hi_bf16(v.y); l.y = lo_bf16(v.y);
  h.z = hi_bf16(v.z); l.z = lo_bf16(v.z);
  h.w = hi_bf16(v.w); l.w = lo_bf16(v.w);
  *(short4v*)hp = h;
  *(short4v*)lp = l;
}

__device__ __forceinline__ void split8(const float4 v0, const float4 v1,
                                       bf16x8* hp, bf16x8* lp) {
  bf16x8 h, l;
  h[0] = hi_bf16(v0.x); l[0] = lo_bf16(v0.x);
  h[1] = hi_bf16(v0.y); l[1] = lo_bf16(v0.y);
  h[2] = hi_bf16(v0.z); l[2] = lo_bf16(v0.z);
  h[3] = hi_bf16(v0.w); l[3] = lo_bf16(v0.w);
  h[4] = hi_bf16(v1.x); l[4] = lo_bf16(v1.x);
  h[5] = hi_bf16(v1.y); l[5] = lo_bf16(v1.y);
  h[6] = hi_bf16(v1.z); l[6] = lo_bf16(v1.z);
  h[7] = hi_bf16(v1.w); l[7] = lo_bf16(v1.w);
  *hp = h; *lp = l;
}

// ---------------- dual-direction projection GEMM, split-bf16 MFMA ----------------
// C[lm][n] = sum_k X[srow(lm)][k]*W[n][k] + b1[n]+b2[n]; lm = chunk-local scan index.
// grid: (N/128, TC, 2 dirs); block 256 = 4 waves in 2x2 (64x64 each).
__global__ __launch_bounds__(256, 2) void proj_gemm2(
    const float* __restrict__ X,
    const float* __restrict__ W0, const float* __restrict__ W1,
    const float* __restrict__ b1f, const float* __restrict__ b2f,
    const float* __restrict__ b1r, const float* __restrict__ b2r,
    float* __restrict__ C0, float* __restrict__ C1,
    int N, int K, const int* __restrict__ lengths, int t0)
{
  __shared__ short Xh[128 * LDK], Xl[128 * LDK];
  __shared__ short Wh[128 * LDK], Wl[128 * LDK];
  const int rev = blockIdx.z;
  const float* __restrict__ W = rev ? W1 : W0;
  const float* __restrict__ bias1 = rev ? b1r : b1f;
  const float* __restrict__ bias2 = rev ? b2r : b2f;
  float* __restrict__ C = rev ? C1 : C0;

  const int tid = threadIdx.x;
  const int m0 = blockIdx.y * 128, n0 = blockIdx.x * 128;
  const int s_step = t0 + blockIdx.y;

  // staging: thread covers rows sr+32p, cols sc..sc+3 of the 128x32 k-tile
  const int sr = tid >> 3;
  const int sc = (tid & 7) * 4;
  const float* px[4];
  const float* pw[4];
#pragma unroll
  for (int p = 0; p < 4; p++) {
    const int r = sr + p * 32;          // r == batch index within tile
    int ss = s_step;
    if (rev) {
      int lb = lengths[r]; if (lb < 1) lb = 1;
      ss = (s_step < lb) ? (lb - 1 - s_step) : s_step;
    }
    px[p] = X + (size_t)(ss * 128 + r) * K;
    pw[p] = W + (size_t)(n0 + r) * K;
  }

  const int lane = tid & 63, w = tid >> 6;
  const int mb = (w & 1) * 64, nb = (w >> 1) * 64;
  const int r16 = lane & 15, quad = lane >> 4;

  f32x4 acc[4][4];
#pragma unroll
  for (int i = 0; i < 4; i++)
#pragma unroll
    for (int j = 0; j < 4; j++) acc[i][j] = (f32x4){0.f, 0.f, 0.f, 0.f};

  for (int k0 = 0; k0 < K; k0 += 32) {
    const int gk = k0 + sc;
    const bool kin = (gk < K);          // K % 4 == 0 -> whole float4 in/out
#pragma unroll
    for (int p = 0; p < 4; p++) {
      float4 xv = {0.f, 0.f, 0.f, 0.f}, wv = {0.f, 0.f, 0.f, 0.f};
      if (kin) { xv = *(const float4*)(px[p] + gk); wv = *(const float4*)(pw[p] + gk); }
      const int ro = (sr + p * 32) * LDK + sc;
      split_f4(xv, &Xh[ro], &Xl[ro]);
      split_f4(wv, &Wh[ro], &Wl[ro]);
    }
    __syncthreads();

    bf16x8 ah[4], al[4], bh[4], bl[4];
#pragma unroll
    for (int mt = 0; mt < 4; mt++) {
      const int ro = (mb + mt * 16 + r16) * LDK + quad * 8;
      ah[mt] = *(const bf16x8*)&Xh[ro];
      al[mt] = *(const bf16x8*)&Xl[ro];
    }
#pragma unroll
    for (int nt = 0; nt < 4; nt++) {
      const int ro = (nb + nt * 16 + r16) * LDK + quad * 8;
      bh[nt] = *(const bf16x8*)&Wh[ro];
      bl[nt] = *(const bf16x8*)&Wl[ro];
    }
#pragma unroll
    for (int mt = 0; mt < 4; mt++)
#pragma unroll
      for (int nt = 0; nt < 4; nt++) {
        acc[mt][nt] = __builtin_amdgcn_mfma_f32_16x16x32_bf16(ah[mt], bh[nt], acc[mt][nt], 0, 0, 0);
        acc[mt][nt] = __builtin_amdgcn_mfma_f32_16x16x32_bf16(ah[mt], bl[nt], acc[mt][nt], 0, 0, 0);
        acc[mt][nt] = __builtin_amdgcn_mfma_f32_16x16x32_bf16(al[mt], bh[nt], acc[mt][nt], 0, 0, 0);
      }
    __syncthreads();
  }

  // epilogue: C/D layout row = quad*4+reg (m), col = lane&15 (n)  [m89-verified]
  float bsum[4];
#pragma unroll
  for (int nt = 0; nt < 4; nt++) {
    const int col = n0 + nb + nt * 16 + r16;
    bsum[nt] = bias1[col] + bias2[col];
  }
#pragma unroll
  for (int mt = 0; mt < 4; mt++) {
    const int row = m0 + mb + mt * 16 + quad * 4;
#pragma unroll
    for (int nt = 0; nt < 4; nt++) {
      const int col = n0 + nb + nt * 16 + r16;
      float* Cp = C + (size_t)row * N + col;
#pragma unroll
      for (int reg = 0; reg < 4; reg++)
        Cp[(size_t)reg * N] = acc[mt][nt][reg] + bsum[nt];
    }
  }
}

// ---------------- attention score GEMM, split-bf16 MFMA, fused tanh*ctx ----------
// scores[m] += sum_n tanh(h2[m]@mlp_w^T + b)[n] * ctx[n]
__global__ __launch_bounds__(256, 2) void attn_gemm(
    const float* __restrict__ X, const float* __restrict__ W,
    const float* __restrict__ mlp_b, const float* __restrict__ ctx,
    float* __restrict__ scores, int M, int N, int K)
{
  __shared__ short Xh[128 * LDK], Xl[128 * LDK];
  __shared__ short Wh[128 * LDK], Wl[128 * LDK];
  const int tid = threadIdx.x;
  const int m0 = blockIdx.y * 128, n0 = blockIdx.x * 128;

  const int sr = tid >> 3;
  const int sc = (tid & 7) * 4;
  const float* px[4];
  const float* pw[4];
#pragma unroll
  for (int p = 0; p < 4; p++) {
    px[p] = X + (size_t)(m0 + sr + p * 32) * K;
    pw[p] = W + (size_t)(n0 + sr + p * 32) * K;
  }

  const int lane = tid & 63, w = tid >> 6;
  const int mb = (w & 1) * 64, nb = (w >> 1) * 64;
  const int r16 = lane & 15, quad = lane >> 4;

  f32x4 acc[4][4];
#pragma unroll
  for (int i = 0; i < 4; i++)
#pragma unroll
    for (int j = 0; j < 4; j++) acc[i][j] = (f32x4){0.f, 0.f, 0.f, 0.f};

  for (int k0 = 0; k0 < K; k0 += 32) {
    const int gk = k0 + sc;
#pragma unroll
    for (int p = 0; p < 4; p++) {
      float4 xv = *(const float4*)(px[p] + gk);
      float4 wv = *(const float4*)(pw[p] + gk);
      const int ro = (sr + p * 32) * LDK + sc;
      split_f4(xv, &Xh[ro], &Xl[ro]);
      split_f4(wv, &Wh[ro], &Wl[ro]);
    }
    __syncthreads();

    bf16x8 ah[4], al[4], bh[4], bl[4];
#pragma unroll
    for (int mt = 0; mt < 4; mt++) {
      const int ro = (mb + mt * 16 + r16) * LDK + quad * 8;
      ah[mt] = *(const bf16x8*)&Xh[ro];
      al[mt] = *(const bf16x8*)&Xl[ro];
    }
#pragma unroll
    for (int nt = 0; nt < 4; nt++) {
      const int ro = (nb + nt * 16 + r16) * LDK + quad * 8;
      bh[nt] = *(const bf16x8*)&Wh[ro];
      bl[nt] = *(const bf16x8*)&Wl[ro];
    }
#pragma unroll
    for (int mt = 0; mt < 4; mt++)
#pragma unroll
      for (int nt = 0; nt < 4; nt++) {
        acc[mt][nt] = __builtin_amdgcn_mfma_f32_16x16x32_bf16(ah[mt], bh[nt], acc[mt][nt], 0, 0, 0);
        acc[mt][nt] = __builtin_amdgcn_mfma_f32_16x16x32_bf16(ah[mt], bl[nt], acc[mt][nt], 0, 0, 0);
        acc[mt][nt] = __builtin_amdgcn_mfma_f32_16x16x32_bf16(al[mt], bh[nt], acc[mt][nt], 0, 0, 0);
      }
    __syncthreads();
  }

  // epilogue: tanh(acc + b)*ctx, reduce over n (4 nt in-thread, then 16 lanes)
  float bb4[4], cc4[4];
#pragma unroll
  for (int nt = 0; nt < 4; nt++) {
    const int col = n0 + nb + nt * 16 + r16;
    bb4[nt] = mlp_b[col];
    cc4[nt] = ctx[col];
  }
#pragma unroll
  for (int mt = 0; mt < 4; mt++) {
#pragma unroll
    for (int reg = 0; reg < 4; reg++) {
      float ssum = 0.f;
#pragma unroll
      for (int nt = 0; nt < 4; nt++)
        ssum += tanhfast(acc[mt][nt][reg] + bb4[nt]) * cc4[nt];
      ssum += __shfl_xor(ssum, 1);
      ssum += __shfl_xor(ssum, 2);
      ssum += __shfl_xor(ssum, 4);
      ssum += __shfl_xor(ssum, 8);
      if (r16 == 0)
        atomicAdd(&scores[m0 + mb + mt * 16 + quad * 4 + reg], ssum);
    }
  }
}

// ---------------- LSTM recurrence chunk (both directions) -- R11 MFMA ------------
// blocks: 256, blk = s*32 + d*16 + g (partners same (d,g), all s -> same XCD).
// Block owns dir d, batches g*8..g*8+7, hdims s*32..s*32+31 (output N = 4 gates x 32).
// Per step: MFMA [16(8b+8pad) x 256] @ [256 x 128] with hi/lo bf16 weights resident
// in VGPRs (bh/bl: 128 VGPR, static indices); gates -> LDS gbuf -> per-cell update;
// h broadcast via sentinel ring (unchanged protocol).
__global__ __launch_bounds__(256, 1) void lstm_rec(
    const float* __restrict__ xgF, const float* __restrict__ xgR,
    const float* __restrict__ whF, const float* __restrict__ whR,
    const int* __restrict__ lengths, float* __restrict__ hout,
    float* __restrict__ ring, float* __restrict__ bbuf, float* __restrict__ cbuf,
    int t0)
{
  __shared__ short Ah[16 * LDA];   // h(t-1) hi-plane: rows 0-7 batches, 8-15 zero
  __shared__ short Al[16 * LDA];   // lo-plane
  __shared__ float gbuf[8 * 128];  // gate pre-acts: [b][gate*32 + hl]

  const int tid = threadIdx.x;
  const int blk = blockIdx.x;
  const int s = blk >> 5;
  const int d = (blk >> 4) & 1;
  const int g = blk & 15;
  const float* __restrict__ xg = d ? xgR : xgF;
  const float* __restrict__ wh = d ? whR : whF;

  const int lane = tid & 63;
  const int w = tid >> 6;              // wave index == gate index
  const int r16 = lane & 15, quad = lane >> 4;

  // cell / staging mapping: thread owns cell (b = g*8+cb, hdim = s*32+hl)
  // and stages A row cb, k = k0..k0+7.
  const int cb = tid >> 5;             // 0..7
  const int hl = tid & 31;             // 0..31
  const int b = g * 8 + cb;
  const int hdim = s * 32 + hl;
  const int k0 = hl * 8;               // 0..248

  // ---- weight fragments (hi/lo bf16), once: 128 VGPR, statically indexed ----
  bf16x8 bh[2][8], bl[2][8];
#pragma unroll
  for (int nt = 0; nt < 2; nt++)
#pragma unroll
    for (int kt = 0; kt < 8; kt++) {
      const float* wr = wh + (size_t)(w * 256 + s * 32 + nt * 16 + r16) * 256
                           + kt * 32 + quad * 8;
      float4 v0 = *(const float4*)(wr);
      float4 v1 = *(const float4*)(wr + 4);
      split8(v0, v1, &bh[nt][kt], &bl[nt][kt]);
    }

  // ---- zero A pad rows 8..15 (stay zero all chunk) ----
  {
    int* za = (int*)(Ah + 8 * LDA);
    int* zb = (int*)(Al + 8 * LDA);
    for (int i = tid; i < (8 * LDA) / 2; i += 256) { za[i] = 0; zb[i] = 0; }
  }

  // ---- initial h(t0-1) and c ----
  float c;
  if (t0 == 0) {
    int* za = (int*)Ah;
    int* zb = (int*)Al;
    for (int i = tid; i < (8 * LDA) / 2; i += 256) { za[i] = 0; zb[i] = 0; }
    c = 0.f;
  } else {
    const float* src = bbuf + ((size_t)d * 128 + g * 8 + cb) * 256 + k0;
    float4 v0 = *(const float4*)src;
    float4 v1 = *(const float4*)(src + 4);
    bf16x8 hv, lv;
    split8(v0, v1, &hv, &lv);
    *(bf16x8*)&Ah[cb * LDA + k0] = hv;
    *(bf16x8*)&Al[cb * LDA + k0] = lv;
    c = cbuf[((size_t)d * 128 + b) * 256 + hdim];
  }
  int lb = lengths[b]; if (lb < 1) lb = 1;

  const float* xr0 = xg + (size_t)b * 1024 + hdim;
  float x0 = xr0[0], x1 = xr0[256], x2 = xr0[512], x3 = xr0[768];
  __syncthreads();

  const int tend = t0 + TC;
  for (int t = t0; t < tend; t++) {
    const int slot = t - t0;
    const bool last = (t == tend - 1);

    // ---- MFMA gate matvec: 48 MFMAs, 6 independent chains ----
    f32x4 aH0 = {0.f,0.f,0.f,0.f}, aM0 = {0.f,0.f,0.f,0.f}, aL0 = {0.f,0.f,0.f,0.f};
    f32x4 aH1 = {0.f,0.f,0.f,0.f}, aM1 = {0.f,0.f,0.f,0.f}, aL1 = {0.f,0.f,0.f,0.f};
#pragma unroll
    for (int kt = 0; kt < 8; kt++) {
      const int ro = r16 * LDA + kt * 32 + quad * 8;
      bf16x8 ahf = *(const bf16x8*)&Ah[ro];
      bf16x8 alf = *(const bf16x8*)&Al[ro];
      aH0 = MFMA16(ahf, bh[0][kt], aH0);
      aM0 = MFMA16(ahf, bl[0][kt], aM0);
      aL0 = MFMA16(alf, bh[0][kt], aL0);
      aH1 = MFMA16(ahf, bh[1][kt], aH1);
      aM1 = MFMA16(ahf, bl[1][kt], aM1);
      aL1 = MFMA16(alf, bh[1][kt], aL1);
    }
    // C layout: m = quad*4+reg (batch; valid m<8), n = r16 -> gbuf[b][w*32 + nt*16 + r16]
    if (quad < 2) {
#pragma unroll
      for (int reg = 0; reg < 4; reg++) {
        gbuf[(quad * 4 + reg) * 128 + w * 32 + r16]      = aH0[reg] + aM0[reg] + aL0[reg];
        gbuf[(quad * 4 + reg) * 128 + w * 32 + 16 + r16] = aH1[reg] + aM1[reg] + aL1[reg];
      }
    }
    __syncthreads();   // gbuf ready; Ah/Al reads complete -> safe to overwrite below

    // ---- cell update (thread owns (b, hdim)) ----
    const float gi = gbuf[cb * 128 +       hl] + x0;
    const float gf = gbuf[cb * 128 +  32 + hl] + x1;
    const float gg = gbuf[cb * 128 +  64 + hl] + x2;
    const float go = gbuf[cb * 128 +  96 + hl] + x3;
    const float si = sigf(gi), sf = sigf(gf);
    const float tg = tanhfast(gg), so = sigf(go);
    c = sf * c + si * tg;
    const float h = so * tanhfast(c);
    if (!last) {
      __hip_atomic_store(&ring[(((size_t)slot * 2 + d) * 128 + b) * 256 + hdim], h,
                         __ATOMIC_RELAXED, __HIP_MEMORY_SCOPE_AGENT);
    } else {
      bbuf[((size_t)d * 128 + b) * 256 + hdim] = h;
    }
    const int tin = d ? ((t < lb) ? (lb - 1 - t) : t) : t;
    hout[((size_t)tin * 128 + b) * 512 + d * 256 + hdim] = h;

    if (!last) {
      // prefetch x(t+1)
      const float* xn = xg + ((size_t)(t + 1 - t0) * 128 + b) * 1024 + hdim;
      const float nx0 = xn[0], nx1 = xn[256], nx2 = xn[512], nx3 = xn[768];

      // spin-stage h(t): 8 dwords (2 float4) per thread, split -> Ah/Al
      const unsigned* su = (const unsigned*)(ring +
          (((size_t)slot * 2 + d) * 128 + g * 8 + cb) * 256 + k0);
      unsigned uv[8];
      int it = 0;
      for (;;) {
        bool ok = true;
#pragma unroll
        for (int j = 0; j < 8; j++) {
          uv[j] = __hip_atomic_load(&su[j],
                                    __ATOMIC_RELAXED, __HIP_MEMORY_SCOPE_AGENT);
          ok &= (uv[j] != 0xFFFFFFFFu);
        }
        if (ok || ++it >= 20000) break;
      }
      float4 v0, v1;
      v0.x = __uint_as_float(uv[0]); v0.y = __uint_as_float(uv[1]);
      v0.z = __uint_as_float(uv[2]); v0.w = __uint_as_float(uv[3]);
      v1.x = __uint_as_float(uv[4]); v1.y = __uint_as_float(uv[5]);
      v1.z = __uint_as_float(uv[6]); v1.w = __uint_as_float(uv[7]);
      bf16x8 hv, lv;
      split8(v0, v1, &hv, &lv);
      *(bf16x8*)&Ah[cb * LDA + k0] = hv;
      *(bf16x8*)&Al[cb * LDA + k0] = lv;

      x0 = nx0; x1 = nx1; x2 = nx2; x3 = nx3;
      __syncthreads();   // A staged for step t+1
    }
  }
  cbuf[((size_t)d * 128 + b) * 256 + hdim] = c;
}

// ---------------- masked softmax over t + weighted sum ----------------
__global__ __launch_bounds__(256) void attn_final(
    const float* __restrict__ h2, const float* __restrict__ scores,
    const int* __restrict__ lengths, float* __restrict__ out)
{
  __shared__ float sl[256];
  __shared__ float red[256];
  const int b = blockIdx.x, tid = threadIdx.x;
  int lb = lengths[b]; if (lb < 1) lb = 1;
  const float sc = scores[(size_t)tid * 128 + b];
  const bool valid = (tid < lb);
  red[tid] = valid ? sc : -1e30f;
  __syncthreads();
  for (int off = 128; off > 0; off >>= 1) {
    if (tid < off) red[tid] = fmaxf(red[tid], red[tid + off]);
    __syncthreads();
  }
  const float mx = red[0];
  __syncthreads();
  const float p = valid ? __expf(sc - mx) : 0.f;
  red[tid] = p;
  __syncthreads();
  for (int off = 128; off > 0; off >>= 1) {
    if (tid < off) red[tid] += red[tid + off];
    __syncthreads();
  }
  const float inv = 1.f / red[0];
  __syncthreads();
  sl[tid] = p * inv;
  __syncthreads();

  float ax = 0.f, ay = 0.f;
  const int dd = tid * 2;
  for (int t = 0; t < 256; t++) {
    const float w = sl[t];
    if (w != 0.f) {
      const float* row = h2 + ((size_t)t * 128 + b) * 512 + dd;
      ax += w * row[0];
      ay += w * row[1];
    }
  }
  float2 r; r.x = ax; r.y = ay;
  *(float2*)(out + (size_t)b * 512 + dd) = r;
}

// ---------------- launch ----------------
extern "C" void kernel_launch(void* const* d_in, const int* in_sizes, int n_in,
                              void* d_out, int out_size, void* d_ws, size_t ws_size,
                              hipStream_t stream) {
  (void)in_sizes; (void)n_in; (void)out_size; (void)ws_size;
  const float* x        = (const float*)d_in[0];
  const int*   lengths  = (const int*)d_in[1];
  const float* w_ih_l0  = (const float*)d_in[2];
  const float* w_hh_l0  = (const float*)d_in[3];
  const float* b_ih_l0  = (const float*)d_in[4];
  const float* b_hh_l0  = (const float*)d_in[5];
  const float* w_ih_l0r = (const float*)d_in[6];
  const float* w_hh_l0r = (const float*)d_in[7];
  const float* b_ih_l0r = (const float*)d_in[8];
  const float* b_hh_l0r = (const float*)d_in[9];
  const float* w_ih_l1  = (const float*)d_in[10];
  const float* w_hh_l1  = (const float*)d_in[11];
  const float* b_ih_l1  = (const float*)d_in[12];
  const float* b_hh_l1  = (const float*)d_in[13];
  const float* w_ih_l1r = (const float*)d_in[14];
  const float* w_hh_l1r = (const float*)d_in[15];
  const float* b_ih_l1r = (const float*)d_in[16];
  const float* b_hh_l1r = (const float*)d_in[17];
  const float* mlp_w    = (const float*)d_in[18];
  const float* mlp_b    = (const float*)d_in[19];
  const float* ctx      = (const float*)d_in[20];
  float* out = (float*)d_out;

  // workspace layout (floats): ~219 MB
  float* ws = (float*)d_ws;
  const size_t XGC    = (size_t)TC * B_ * G4H;        // 8,388,608
  const size_t H_SZ   = (size_t)T_ * B_ * H2;         // 16,777,216
  const size_t RINGSZ = (size_t)TC * 2 * B_ * H_;     // 4,194,304 floats = 16 MB
  float* xgA    = ws;
  float* xgB    = xgA + XGC;
  float* h1     = xgB + XGC;
  float* h2     = h1 + H_SZ;
  float* ring   = h2 + H_SZ;
  float* bbuf   = ring + RINGSZ;                      // 65,536
  float* cbuf   = bbuf + 65536;                       // 65,536
  float* scores = cbuf + 65536;                       // 32,768

  (void)hipMemsetAsync(scores, 0, 32768 * 4, stream);

  dim3 blk(256);
  const dim3 pgrid(G4H / 128, TC, 2);   // (8, 64, 2 directions)

  // layer 0 (K=300), chunked over time
  for (int c = 0; c < T_ / TC; c++) {
    const int t0 = c * TC;
    proj_gemm2<<<pgrid, blk, 0, stream>>>(x, w_ih_l0, w_ih_l0r,
                                          b_ih_l0, b_hh_l0, b_ih_l0r, b_hh_l0r,
                                          xgA, xgB, G4H, D_, lengths, t0);
    (void)hipMemsetAsync(ring, 0xFF, RINGSZ * 4, stream);   // sentinel = 0xFFFFFFFF
    lstm_rec<<<256, blk, 0, stream>>>(xgA, xgB, w_hh_l0, w_hh_l0r, lengths, h1,
                                      ring, bbuf, cbuf, t0);
  }
  // layer 1 (K=512)
  for (int c = 0; c < T_ / TC; c++) {
    const int t0 = c * TC;
    proj_gemm2<<<pgrid, blk, 0, stream>>>(h1, w_ih_l1, w_ih_l1r,
                                          b_ih_l1, b_hh_l1, b_ih_l1r, b_hh_l1r,
                                          xgA, xgB, G4H, H2, lengths, t0);
    (void)hipMemsetAsync(ring, 0xFF, RINGSZ * 4, stream);
    lstm_rec<<<256, blk, 0, stream>>>(xgA, xgB, w_hh_l1, w_hh_l1r, lengths, h2,
                                      ring, bbuf, cbuf, t0);
  }
  // attention (M=32768, N=512, K=512)
  attn_gemm<<<dim3(H2 / 128, (T_ * B_) / 128), blk, 0, stream>>>(h2, mlp_w, mlp_b, ctx, scores, T_ * B_, H2, H2);
  attn_final<<<B_, blk, 0, stream>>>(h2, scores, lengths, out);
}